// Round 1
// baseline (4193.844 us; speedup 1.0000x reference)
//
#include <hip/hip_runtime.h>
#include <cstdio>

#define B_   256
#define H_   512
#define G4_  2048
#define T_   326
#define OUT_ 9

typedef __attribute__((ext_vector_type(8))) short s16x8;
typedef __attribute__((ext_vector_type(4))) float f32x4;

__device__ inline unsigned short to_bf16(float f) {
    unsigned int u = __builtin_bit_cast(unsigned int, f);
    unsigned int r = (u + 0x7fffu + ((u >> 16) & 1u)) >> 16;  // RNE
    return (unsigned short)r;
}

__device__ inline float sigmoidf_(float x) { return 1.0f / (1.0f + __expf(-x)); }

// ---------------- prep kernels ----------------

// Combined weights: Wc = bf16(W_ih + W_hh)  [2048][512]
// Concat weights:   Wcat[n] = [bf16(W_ih[n]) | bf16(W_hh[n])]  [2048][1024]
// Combined bias:    bc = b_ih + b_hh  [2048] f32
__global__ void prep_weights(const float* __restrict__ Wih, const float* __restrict__ Whh,
                             const float* __restrict__ bih, const float* __restrict__ bhh,
                             unsigned short* __restrict__ Wc, unsigned short* __restrict__ Wcat,
                             float* __restrict__ bc) {
    int idx = blockIdx.x * 256 + threadIdx.x;      // < 2048*512
    int n = idx >> 9, k = idx & 511;
    float wi = Wih[idx], wh = Whh[idx];
    Wc[idx] = to_bf16(wi + wh);
    Wcat[(n << 10) + k]       = to_bf16(wi);
    Wcat[(n << 10) + 512 + k] = to_bf16(wh);
    if (k == 0) bc[n] = bih[n] + bhh[n];
}

__global__ void prep_w1(const float* __restrict__ W1, unsigned short* __restrict__ W1b) {
    int idx = blockIdx.x * 256 + threadIdx.x;      // < 512*512
    W1b[idx] = to_bf16(W1[idx]);
}

// W2 padded to 16 rows (rows 9..15 zero), bf16  [16][512]
__global__ void prep_w2(const float* __restrict__ W2, unsigned short* __restrict__ W2b) {
    int idx = blockIdx.x * 256 + threadIdx.x;      // < 16*512
    int o = idx >> 9, k = idx & 511;
    W2b[idx] = (o < OUT_) ? to_bf16(W2[o * H_ + k]) : (unsigned short)0;
}

// xcat[b] = [bf16(x[b]) | bf16(hx0[b])]  [256][1024]
__global__ void prep_x(const float* __restrict__ x, const float* __restrict__ hx0,
                       unsigned short* __restrict__ xcat) {
    int idx = blockIdx.x * 256 + threadIdx.x;      // < 256*512
    int b = idx >> 9, k = idx & 511;
    xcat[(b << 10) + k]       = to_bf16(x[idx]);
    xcat[(b << 10) + 512 + k] = to_bf16(hx0[idx]);
}

// ---------------- LSTM step ----------------
// One kernel launch per time step (kernel boundary = grid barrier).
// Grid: 128 WGs x 256 thr. WG = (row-tile of 16) x (hidden-group of 64).
// Each wave owns a 16-wide hidden slice and computes all 4 gates for it,
// so the c/h update is WG-local. A = h_{t-1} bf16 [256][KLEN], W = [2048][KLEN]
// row-major (B^T form): both MFMA fragments load as contiguous 16B.
template <int KLEN>
__global__ __launch_bounds__(256) void lstm_step(
    const unsigned short* __restrict__ A,
    const unsigned short* __restrict__ W,
    const float* __restrict__ bc,
    const float* __restrict__ c_in,
    float* __restrict__ c_out,
    unsigned short* __restrict__ h_out) {
    const int lane = threadIdx.x & 63;
    const int wave = threadIdx.x >> 6;
    const int mn = lane & 15, q = lane >> 4;
    const int rt = blockIdx.x & 15;                  // row tile (16 rows)
    const int hb = (blockIdx.x >> 4) * 64 + wave * 16;  // hidden base for wave

    const unsigned short* ap  = A + (size_t)(rt * 16 + mn) * KLEN + q * 8;
    const unsigned short* wp0 = W + (size_t)(0 * H_ + hb + mn) * KLEN + q * 8;
    const unsigned short* wp1 = W + (size_t)(1 * H_ + hb + mn) * KLEN + q * 8;
    const unsigned short* wp2 = W + (size_t)(2 * H_ + hb + mn) * KLEN + q * 8;
    const unsigned short* wp3 = W + (size_t)(3 * H_ + hb + mn) * KLEN + q * 8;

    f32x4 acc0 = {0.f, 0.f, 0.f, 0.f}, acc1 = {0.f, 0.f, 0.f, 0.f};
    f32x4 acc2 = {0.f, 0.f, 0.f, 0.f}, acc3 = {0.f, 0.f, 0.f, 0.f};
#pragma unroll 4
    for (int k0 = 0; k0 < KLEN; k0 += 32) {
        s16x8 a  = *reinterpret_cast<const s16x8*>(ap + k0);
        s16x8 w0 = *reinterpret_cast<const s16x8*>(wp0 + k0);
        s16x8 w1 = *reinterpret_cast<const s16x8*>(wp1 + k0);
        s16x8 w2 = *reinterpret_cast<const s16x8*>(wp2 + k0);
        s16x8 w3 = *reinterpret_cast<const s16x8*>(wp3 + k0);
        acc0 = __builtin_amdgcn_mfma_f32_16x16x32_bf16(a, w0, acc0, 0, 0, 0);
        acc1 = __builtin_amdgcn_mfma_f32_16x16x32_bf16(a, w1, acc1, 0, 0, 0);
        acc2 = __builtin_amdgcn_mfma_f32_16x16x32_bf16(a, w2, acc2, 0, 0, 0);
        acc3 = __builtin_amdgcn_mfma_f32_16x16x32_bf16(a, w3, acc3, 0, 0, 0);
    }

    // epilogue: gates (i,f,g,o) for hidden col j, rows rt*16 + q*4 + r
    const int j = hb + mn;
    const float bi = bc[j], bfv = bc[H_ + j], bg = bc[2 * H_ + j], bo = bc[3 * H_ + j];
#pragma unroll
    for (int r = 0; r < 4; ++r) {
        const int row = rt * 16 + q * 4 + r;
        const float iv = sigmoidf_(acc0[r] + bi);
        const float fv = sigmoidf_(acc1[r] + bfv);
        const float gv = tanhf(acc2[r] + bg);
        const float ov = sigmoidf_(acc3[r] + bo);
        const float co = c_in[row * H_ + j];
        const float cn = fv * co + iv * gv;
        c_out[row * H_ + j] = cn;
        h_out[row * H_ + j] = to_bf16(ov * tanhf(cn));
    }
}

// ---------------- deferred MLP head ----------------
// Grid: 326*4 WGs x 256 thr. WG = (t, 64-row tile). Waves split N (128 each)
// for z = relu(h@W1.T + b1); z goes through LDS (32 rows/pass, padded stride)
// to convert C-layout -> A-layout; y = z@W2pad.T via MFMA (N=16, 9 real).
__global__ __launch_bounds__(256) void mlp_kernel(
    const unsigned short* __restrict__ h_hist,  // [326][256][512] bf16
    const unsigned short* __restrict__ W1b,     // [512][512] bf16
    const float* __restrict__ b1,               // [512]
    const unsigned short* __restrict__ W2b,     // [16][512] bf16 (padded)
    const float* __restrict__ b2,               // [9]
    float* __restrict__ out) {                  // [256][326][9]
    constexpr int ZS = 520;                     // ushort stride: breaks bank alignment
    __shared__ unsigned short z_lds[32 * ZS];

    const int lane = threadIdx.x & 63;
    const int wave = threadIdx.x >> 6;
    const int mn = lane & 15, q = lane >> 4;
    const int t = blockIdx.x >> 2, mt = blockIdx.x & 3;

    const unsigned short* Abase = h_hist + ((size_t)t * B_ + mt * 64) * H_;
    const int nb = wave * 128;

    f32x4 zero4 = {0.f, 0.f, 0.f, 0.f};
    f32x4 acc[4][8];
#pragma unroll
    for (int m4 = 0; m4 < 4; ++m4)
#pragma unroll
        for (int nt = 0; nt < 8; ++nt) acc[m4][nt] = zero4;

    for (int k0 = 0; k0 < 512; k0 += 32) {
        s16x8 a[4];
#pragma unroll
        for (int m4 = 0; m4 < 4; ++m4)
            a[m4] = *reinterpret_cast<const s16x8*>(Abase + (size_t)(m4 * 16 + mn) * H_ + k0 + q * 8);
#pragma unroll
        for (int nt = 0; nt < 8; ++nt) {
            s16x8 b = *reinterpret_cast<const s16x8*>(W1b + (size_t)(nb + nt * 16 + mn) * H_ + k0 + q * 8);
#pragma unroll
            for (int m4 = 0; m4 < 4; ++m4)
                acc[m4][nt] = __builtin_amdgcn_mfma_f32_16x16x32_bf16(a[m4], b, acc[m4][nt], 0, 0, 0);
        }
    }

    float b1v[8];
#pragma unroll
    for (int nt = 0; nt < 8; ++nt) b1v[nt] = b1[nb + nt * 16 + mn];

    for (int pass = 0; pass < 2; ++pass) {
        __syncthreads();  // protect z_lds reuse across passes
#pragma unroll
        for (int m4i = 0; m4i < 2; ++m4i) {
            const int m4 = 2 * pass + m4i;
            const int rl = m4i * 16 + q * 4;  // local row base in z_lds
#pragma unroll
            for (int nt = 0; nt < 8; ++nt) {
                const int col = nb + nt * 16 + mn;
#pragma unroll
                for (int r = 0; r < 4; ++r) {
                    float v = acc[m4][nt][r] + b1v[nt];
                    v = v > 0.f ? v : 0.f;
                    z_lds[(rl + r) * ZS + col] = to_bf16(v);
                }
            }
        }
        __syncthreads();
        if (wave < 2) {  // two 16-row M-tiles per pass
            f32x4 yacc = {0.f, 0.f, 0.f, 0.f};
#pragma unroll 4
            for (int k0 = 0; k0 < 512; k0 += 32) {
                s16x8 az = *reinterpret_cast<const s16x8*>(&z_lds[(wave * 16 + mn) * ZS + k0 + q * 8]);
                s16x8 bw = *reinterpret_cast<const s16x8*>(W2b + (size_t)mn * H_ + k0 + q * 8);
                yacc = __builtin_amdgcn_mfma_f32_16x16x32_bf16(az, bw, yacc, 0, 0, 0);
            }
            if (mn < OUT_) {  // C-layout: col = o = mn, row = q*4 + r
                const float bias = b2[mn];
#pragma unroll
                for (int r = 0; r < 4; ++r) {
                    const int row_local = pass * 32 + wave * 16 + q * 4 + r;
                    const int b = mt * 64 + row_local;
                    out[(size_t)b * (T_ * OUT_) + t * OUT_ + mn] = yacc[r] + bias;
                }
            }
        }
    }
}

// ---------------- host launch ----------------
extern "C" void kernel_launch(void* const* d_in, const int* in_sizes, int n_in,
                              void* d_out, int out_size, void* d_ws, size_t ws_size,
                              hipStream_t stream) {
    (void)in_sizes; (void)n_in; (void)out_size;
    const float* x   = (const float*)d_in[0];
    const float* hx0 = (const float*)d_in[1];
    const float* cx0 = (const float*)d_in[2];
    const float* Wih = (const float*)d_in[3];
    const float* Whh = (const float*)d_in[4];
    const float* bih = (const float*)d_in[5];
    const float* bhh = (const float*)d_in[6];
    const float* W1  = (const float*)d_in[7];
    const float* b1  = (const float*)d_in[8];
    const float* W2  = (const float*)d_in[9];
    const float* b2  = (const float*)d_in[10];
    float* out = (float*)d_out;

    char* p = (char*)d_ws;
    size_t off = 0;
    auto alloc = [&](size_t bytes) {
        void* r = p + off;
        off = (off + bytes + 255) & ~(size_t)255;
        return r;
    };
    unsigned short* Wc     = (unsigned short*)alloc((size_t)G4_ * H_ * 2);
    unsigned short* Wcat   = (unsigned short*)alloc((size_t)G4_ * 1024 * 2);
    unsigned short* W1b    = (unsigned short*)alloc((size_t)H_ * H_ * 2);
    unsigned short* W2b    = (unsigned short*)alloc((size_t)16 * H_ * 2);
    float*          bc     = (float*)alloc((size_t)G4_ * 4);
    unsigned short* xcat   = (unsigned short*)alloc((size_t)B_ * 1024 * 2);
    float*          cbuf   = (float*)alloc((size_t)B_ * H_ * 4);
    unsigned short* h_hist = (unsigned short*)alloc((size_t)T_ * B_ * H_ * 2);
    if (off > ws_size) {
        fprintf(stderr, "kernel_launch: ws too small: need %zu have %zu\n", off, ws_size);
        return;
    }

    prep_weights<<<G4_ * H_ / 256, 256, 0, stream>>>(Wih, Whh, bih, bhh, Wc, Wcat, bc);
    prep_w1<<<H_ * H_ / 256, 256, 0, stream>>>(W1, W1b);
    prep_w2<<<16 * H_ / 256, 256, 0, stream>>>(W2, W2b);
    prep_x<<<B_ * H_ / 256, 256, 0, stream>>>(x, hx0, xcat);

    // step 0: input = [x | hx0], weights = [W_ih | W_hh], K = 1024
    lstm_step<1024><<<128, 256, 0, stream>>>(xcat, Wcat, bc, cx0, cbuf, h_hist);
    // steps 1..325: input = h (bf16), weights = W_ih + W_hh, K = 512
    for (int t = 1; t < T_; ++t)
        lstm_step<512><<<128, 256, 0, stream>>>(h_hist + (size_t)(t - 1) * B_ * H_, Wc, bc,
                                                cbuf, cbuf, h_hist + (size_t)t * B_ * H_);

    mlp_kernel<<<T_ * 4, 256, 0, stream>>>(h_hist, W1b, b1, W2b, b2, out);
}